// Round 14
// baseline (63.575 us; speedup 1.0000x reference)
//
#include <hip/hip_runtime.h>
#include <stdint.h>

#define NF 24
#define FD 2000
#define VOCABSZ 48000
#define ED 64
#define H1D 64
#define H2D 32
#define NPAIR 276
#define BATCH 4096
#define NSEL 16
#define NTILE 256            // BATCH/16 == grid size (1 block/CU, co-resident)
#define PBASE 49152          // P region (after 48KB emb)
#define SGB   147456         // sg f16 [276][16]  (8832 B)
#define MEANB 156288         // means f32 [276]   (1104 B)
#define SELB  157392         // sel i32 [16]      (64 B)
#define OLDB  157456         // arrival rank i32  (16 B pad)

typedef _Float16 f16x8 __attribute__((ext_vector_type(8)));
typedef _Float16 f16x2 __attribute__((ext_vector_type(2)));
typedef float f32x4 __attribute__((ext_vector_type(4)));

union U4 { f16x8 v; uint32_t u[4]; uint4 q; };
union H2U { f16x2 h; uint32_t u; };

__device__ __forceinline__ uint32_t pkrtz(float lo, float hi){
  uint32_t r; asm("v_cvt_pkrtz_f16_f32 %0, %1, %2" : "=v"(r) : "v"(lo), "v"(hi)); return r;
}
__device__ __forceinline__ uint32_t pk_add(uint32_t a, uint32_t b){
  uint32_t r; asm("v_pk_add_f16 %0, %1, %2" : "=v"(r) : "v"(a), "v"(b)); return r;
}
__device__ __forceinline__ uint32_t pk_mul(uint32_t a, uint32_t b){
  uint32_t r; asm("v_pk_mul_f16 %0, %1, %2" : "=v"(r) : "v"(a), "v"(b)); return r;
}
__device__ __forceinline__ uint32_t pk_relu(uint32_t a){
  uint32_t r; asm("v_pk_max_f16 %0, %1, %2" : "=v"(r) : "v"(a), "v"(0u)); return r;
}
__device__ __forceinline__ float fdot2(uint32_t a, uint32_t b, float c){
  H2U ua, ub; ua.u = a; ub.u = b;
  return __builtin_amdgcn_fdot2(ua.h, ub.h, c, false);
}
#define DPP_ADD(v, ctrl) \
  (v) += __int_as_float(__builtin_amdgcn_update_dpp(0, __float_as_int(v), (ctrl), 0xF, 0xF, true))

// Sum across the 4 16-lane rows via VALU-crossbar permlane swaps (no LDS port).
__device__ __forceinline__ float rowsum4(float v){
  float a = v, b;
  asm volatile("v_mov_b32 %0, %1" : "=v"(b) : "v"(a));
  asm volatile("v_permlane16_swap_b32 %0, %1" : "+v"(a), "+v"(b));
  a = a + b;
  asm volatile("v_mov_b32 %0, %1" : "=v"(b) : "v"(a));
  asm volatile("v_permlane32_swap_b32 %0, %1" : "+v"(a), "+v"(b));
  return a + b;
}

// ============ single persistent kernel: proj + pair-MLP + select + final ============
// Grid MUST be 256 blocks (1/CU, all co-resident). Phases A/B/C proven (R12).
// After phase C: per-block release atomicAdd on cnt; last arrival computes
// means+top16 once, publishes sel, release-stores flag; others spin (tid0).
__global__ __launch_bounds__(1024) void k_all(
    const int* __restrict__ x, const float* __restrict__ tables,
    const float* __restrict__ w1, const float* __restrict__ b1,
    const float* __restrict__ w2, const float* __restrict__ b2,
    const float* __restrict__ w3, const float* __restrict__ b3,
    const float* __restrict__ proj_w, const float* __restrict__ fc_w,
    const float* __restrict__ fc_b, const float* __restrict__ proj_b,
    const float* __restrict__ bias,
    float* __restrict__ part, int* __restrict__ selg,
    int* __restrict__ cnt, int* __restrict__ flag,
    float* __restrict__ out){
  __shared__ __align__(16) char smem[157472];
  float* means_lds = (float*)(smem + MEANB);
  int*   sel_lds   = (int*)(smem + SELB);
  int*   old_lds   = (int*)(smem + OLDB);

  const int tid  = threadIdx.x;
  const int bt   = blockIdx.x;
  const int lane = tid & 63;
  const int w    = tid >> 6;         // 0..15
  const int n    = lane & 15;
  const int kg   = lane >> 4;

  const int half = w >> 3;           // 0: Pt, 1: Pb
  const int oq   = (w >> 1) & 3;
  const int fg   = w & 1;
  const int isPt = (half == 0);
  const float b3v = b3[0];
  const float fcb = fc_b[0], pjb = proj_b[0], bsv = bias[0];

  // ---- w1 B-frags + folded b1 (phase B operands) ----
  const int o = 16*oq + n;
  U4 wp0, wp1;
  {
    const float* wsrc = w1 + (size_t)(isPt ? 0 : ED)*H1D + o;
    #pragma unroll
    for(int j=0;j<8;j++) wp0.v[j] = (_Float16)wsrc[(kg*8+j)*H1D];
    #pragma unroll
    for(int j=0;j<8;j++) wp1.v[j] = (_Float16)wsrc[(32+kg*8+j)*H1D];
  }
  const float b1v = isPt ? b1[o] : 0.f;

  // ---- w2 frags (A-frag for swapped phase-C MFMA) ----
  U4 wf[2][2];   // [khalf][ohalf]
  #pragma unroll
  for(int kh=0;kh<2;kh++)
    #pragma unroll
    for(int nh=0;nh<2;nh++)
      #pragma unroll
      for(int q2=0;q2<4;q2++){
        float lo = w2[(kg*8 + 2*q2     + 32*kh)*H2D + n + 16*nh];
        float hi = w2[(kg*8 + 2*q2 + 1 + 32*kh)*H2D + n + 16*nh];
        wf[kh][nh].u[q2] = pkrtz(lo, hi);
      }
  float b2r[2][4], w3r[2][4];
  #pragma unroll
  for(int oh=0;oh<2;oh++)
    #pragma unroll
    for(int r=0;r<4;r++){
      b2r[oh][r] = b2[16*oh + kg*4 + r];
      w3r[oh][r] = w3[16*oh + kg*4 + r];
    }

  // ---- proj_w slice packed f16 ----
  uint32_t pw2[8];
  #pragma unroll
  for(int j=0;j<8;j++) pw2[j] = pkrtz(proj_w[kg*16 + 2*j], proj_w[kg*16 + 2*j + 1]);

  // ---- phase A: gather 16 rows x 24 fields -> f16 LDS (swizzled) ----
  #pragma unroll
  for(int i=0;i<3;i++){
    int c = i*1024 + tid;         // 0..3071
    int rid = c >> 3;             // f*16 + b
    int qc = c & 7;               // 16B (8 f16) chunk
    int f = rid >> 4, b = rid & 15;
    int xv = x[(bt*16 + b)*NF + f];
    const float4* rp = (const float4*)(tables + ((size_t)f*VOCABSZ + (size_t)f*FD + (size_t)xv)*ED + qc*8);
    float4 v0 = rp[0], v1 = rp[1];
    uint4 pk;
    pk.x = pkrtz(v0.x, v0.y); pk.y = pkrtz(v0.z, v0.w);
    pk.z = pkrtz(v1.x, v1.y); pk.w = pkrtz(v1.z, v1.w);
    uint32_t db = ((uint32_t)(f*2048 + b*128 + qc*16)) ^ ((uint32_t)(b&7)<<4);
    *(uint4*)(smem + db) = pk;
  }
  __syncthreads();

  // ---- phase B: P = emb @ w1half (+b1) via MFMA; element-wise b16 stores ----
  {
    const uint32_t rswz = ((uint32_t)(n&7))<<4;
    const int slab0 = isPt ? 0 : 24;
    for(int ff=0; ff<12; ff++){
      int f = fg*12 + ff;
      U4 a0, a1;
      a0.q = *(const uint4*)(smem + (((uint32_t)(f*2048 + n*128      + kg*16)) ^ rswz));
      a1.q = *(const uint4*)(smem + (((uint32_t)(f*2048 + n*128 + 64 + kg*16)) ^ rswz));
      f32x4 acc = {b1v, b1v, b1v, b1v};
      acc = __builtin_amdgcn_mfma_f32_16x16x32_f16(a0.v, wp0.v, acc, 0,0,0);
      acc = __builtin_amdgcn_mfma_f32_16x16x32_f16(a1.v, wp1.v, acc, 0,0,0);
      int sl = slab0 + f;
      #pragma unroll
      for(int r=0;r<4;r++){
        int bo = kg*4 + r;
        uint32_t db = ((uint32_t)(PBASE + sl*2048 + bo*128 + o*2)) ^ (((uint32_t)(bo&7))<<4);
        *(_Float16*)(smem + db) = (_Float16)acc[r];
      }
    }
  }
  __syncthreads();

  // ---- phase C: pair loop over 16 waves (proven R12 structure) ----
  {
    int p0, np;
    if(w < 4){ np = 18; p0 = w*18; } else { np = 17; p0 = 72 + (w-4)*17; }
    int ii = 0, rem = p0;
    while(rem >= (NF-1-ii)){ rem -= (NF-1-ii); ii++; }
    int jj = ii + 1 + rem;

    const uint32_t aswz = ((uint32_t)(n&7))<<4;
    const uint32_t rowoff = (uint32_t)n*128;
    const uint32_t qoff = (uint32_t)kg*16;
    const uint32_t kg32 = (uint32_t)kg*32;

    int cached_i = -1;
    U4 ta0, ta1, ei0, ei1;

    for(int t=0;t<np;t++){
      int p = p0 + t;
      if(ii != cached_i){
        uint32_t tb = (uint32_t)(PBASE + ii*2048) + rowoff;
        ta0.q = *(const uint4*)(smem + ((tb + qoff     ) ^ aswz));
        ta1.q = *(const uint4*)(smem + ((tb + qoff + 64) ^ aswz));
        uint32_t ebi = (uint32_t)(ii*2048) + rowoff + kg32;
        ei0.q = *(const uint4*)(smem + ((ebi     ) ^ aswz));
        ei1.q = *(const uint4*)(smem + ((ebi + 16) ^ aswz));
        cached_i = ii;
      }
      uint32_t ub = (uint32_t)(PBASE + (24+jj)*2048) + rowoff;
      uint4 c0 = *(const uint4*)(smem + ((ub + qoff     ) ^ aswz));
      uint4 c1 = *(const uint4*)(smem + ((ub + qoff + 64) ^ aswz));
      uint32_t ebj = (uint32_t)(jj*2048) + rowoff + kg32;
      U4 ej0, ej1;
      ej0.q = *(const uint4*)(smem + ((ebj     ) ^ aswz));
      ej1.q = *(const uint4*)(smem + ((ebj + 16) ^ aswz));

      U4 h0, h1;
      h0.u[0]=pk_relu(pk_add(ta0.u[0],c0.x)); h0.u[1]=pk_relu(pk_add(ta0.u[1],c0.y));
      h0.u[2]=pk_relu(pk_add(ta0.u[2],c0.z)); h0.u[3]=pk_relu(pk_add(ta0.u[3],c0.w));
      h1.u[0]=pk_relu(pk_add(ta1.u[0],c1.x)); h1.u[1]=pk_relu(pk_add(ta1.u[1],c1.y));
      h1.u[2]=pk_relu(pk_add(ta1.u[2],c1.z)); h1.u[3]=pk_relu(pk_add(ta1.u[3],c1.w));

      f32x4 acc0 = {0.f,0.f,0.f,0.f}, acc1 = {0.f,0.f,0.f,0.f};
      acc0 = __builtin_amdgcn_mfma_f32_16x16x32_f16(wf[0][0].v, h0.v, acc0, 0,0,0);
      acc0 = __builtin_amdgcn_mfma_f32_16x16x32_f16(wf[1][0].v, h1.v, acc0, 0,0,0);
      acc1 = __builtin_amdgcn_mfma_f32_16x16x32_f16(wf[0][1].v, h0.v, acc1, 0,0,0);
      acc1 = __builtin_amdgcn_mfma_f32_16x16x32_f16(wf[1][1].v, h1.v, acc1, 0,0,0);

      float gp = 0.f;
      #pragma unroll
      for(int q=0;q<4;q++) gp = fdot2(pk_mul(ei0.u[q], ej0.u[q]), pw2[q],   gp);
      #pragma unroll
      for(int q=0;q<4;q++) gp = fdot2(pk_mul(ei1.u[q], ej1.u[q]), pw2[4+q], gp);
      gp = rowsum4(gp);                      // g[p][b=n], all lanes

      float tsum = 0.f;
      #pragma unroll
      for(int r=0;r<4;r++){
        float v0 = acc0[r] + b2r[0][r]; v0 = v0>0.f?v0:0.f;
        float v1 = acc1[r] + b2r[1][r]; v1 = v1>0.f?v1:0.f;
        tsum += v0*w3r[0][r] + v1*w3r[1][r];
      }
      tsum = rowsum4(tsum);
      float sc = tsum + b3v;                 // score[p][b=n], all lanes

      if(lane < 16) *(_Float16*)(smem + SGB + p*32 + lane*2) = (_Float16)(sc * gp);

      float d = sc;
      DPP_ADD(d, 0x111);
      DPP_ADD(d, 0x112);
      DPP_ADD(d, 0x114);
      DPP_ADD(d, 0x118);
      if(lane == 15) part[(size_t)p*NTILE + bt] = d;

      if(++jj == NF){ ii++; jj = ii+1; }
    }
  }
  __syncthreads();   // all part stores drained (vmcnt 0 before barrier)

  // ---- arrival count (release: flushes this XCD's L2) ----
  if(tid == 0)
    old_lds[0] = __hip_atomic_fetch_add(cnt, 1, __ATOMIC_ACQ_REL, __HIP_MEMORY_SCOPE_AGENT);
  __syncthreads();

  if(old_lds[0] == NTILE-1){
    // ---- last block: means (parallel, fixed tree) + top-16, publish sel ----
    {
      int p = tid >> 2, q = tid & 3;
      const float4* pp = (const float4*)(part + (size_t)p*NTILE + q*64);
      float4 s4 = {0.f,0.f,0.f,0.f};
      #pragma unroll
      for(int i=0;i<16;i++){
        float4 v = pp[i];
        s4.x += v.x; s4.y += v.y; s4.z += v.z; s4.w += v.w;
      }
      float s = (s4.x + s4.y) + (s4.z + s4.w);
      s += __shfl_xor(s, 1, 64);
      s += __shfl_xor(s, 2, 64);
      if(q == 0 && p < 256) means_lds[p] = s;
      if(tid < 80){
        int p2 = 256 + (tid >> 2);
        const float4* pp2 = (const float4*)(part + (size_t)p2*NTILE + q*64);
        float4 t4 = {0.f,0.f,0.f,0.f};
        #pragma unroll
        for(int i=0;i<16;i++){
          float4 v = pp2[i];
          t4.x += v.x; t4.y += v.y; t4.z += v.z; t4.w += v.w;
        }
        float s2 = (t4.x + t4.y) + (t4.z + t4.w);
        s2 += __shfl_xor(s2, 1, 64);
        s2 += __shfl_xor(s2, 2, 64);
        if(q == 0) means_lds[p2] = s2;
      }
    }
    __syncthreads();
    if(tid < 64){
      int l = tid;
      float v[5];
      #pragma unroll
      for(int q=0;q<5;q++){
        int i = l + q*64;
        v[q] = (i < NPAIR) ? means_lds[i] : -3.0e38f;
      }
      for(int s=0;s<NSEL;s++){
        float bv = v[0]; int bslot = 0;
        #pragma unroll
        for(int q=1;q<5;q++){ if(v[q] > bv){ bv = v[q]; bslot = q; } }
        int bi = l + bslot*64;
        float cv = bv; int ci = bi;
        #pragma unroll
        for(int m=1;m<64;m<<=1){
          float ov = __shfl_xor(cv, m, 64);
          int   oi = __shfl_xor(ci, m, 64);
          if(ov > cv || (ov == cv && oi < ci)){ cv = ov; ci = oi; }
        }
        if(l == 0) sel_lds[s] = ci;
        if(bi == ci) v[bslot] = -3.0e38f;
      }
    }
    __syncthreads();
    if(tid < NSEL) selg[tid] = sel_lds[tid];
    __syncthreads();   // selg stores drained to L2 before release
    if(tid == 0)
      __hip_atomic_store(flag, 1, __ATOMIC_RELEASE, __HIP_MEMORY_SCOPE_AGENT);
  } else {
    // ---- other blocks: spin-sleep on flag, then pull sel ----
    if(tid == 0){
      while(__hip_atomic_load(flag, __ATOMIC_RELAXED, __HIP_MEMORY_SCOPE_AGENT) == 0)
        __builtin_amdgcn_s_sleep(8);
      (void)__hip_atomic_load(flag, __ATOMIC_ACQUIRE, __HIP_MEMORY_SCOPE_AGENT);
    }
    __syncthreads();
    if(tid < NSEL) sel_lds[tid] = selg[tid];
    __syncthreads();
  }

  // ---- final phase: this block's 16 rows from LDS-resident sg ----
  {
    int row = w;                 // wave per row
    int brow = bt*16 + row;
    float v = 0.f;
    if(lane < NSEL){
      v = (float)(*(const _Float16*)(smem + SGB + sel_lds[lane]*32 + row*2));
    } else if(lane >= 32 && lane < 32+NF){
      int fl = lane - 32;
      v = fc_w[x[brow*NF + fl] + fl*FD];
    }
    #pragma unroll
    for(int m=1;m<64;m<<=1) v += __shfl_xor(v, m, 64);
    if(lane == 0) out[brow] = v + fcb + pjb + bsv;
  }
}

extern "C" void kernel_launch(void* const* d_in, const int* in_sizes, int n_in,
                              void* d_out, int out_size, void* d_ws, size_t ws_size,
                              hipStream_t stream){
  const int*   x      = (const int*)  d_in[0];
  const float* tables = (const float*)d_in[1];
  const float* fc_w   = (const float*)d_in[2];
  const float* fc_b   = (const float*)d_in[3];
  const float* w1     = (const float*)d_in[4];
  const float* b1     = (const float*)d_in[5];
  const float* w2     = (const float*)d_in[6];
  const float* b2     = (const float*)d_in[7];
  const float* w3     = (const float*)d_in[8];
  const float* b3     = (const float*)d_in[9];
  const float* proj_w = (const float*)d_in[10];
  const float* proj_b = (const float*)d_in[11];
  const float* bias   = (const float*)d_in[12];
  float* out = (float*)d_out;

  float* part = (float*)d_ws;                    // 276*256 f32 [pair][tile]
  int*   selg = (int*)(part + (size_t)NPAIR*NTILE);  // 16 i32
  int*   ctrl = selg + 16;                       // cnt, flag

  hipMemsetAsync(ctrl, 0, 8, stream);            // re-arm barrier each replay
  k_all<<<NTILE, 1024, 0, stream>>>(x, tables, w1, b1, w2, b2, w3, b3,
                                    proj_w, fc_w, fc_b, proj_b, bias,
                                    part, selg, ctrl, ctrl+1, out);
}

// Round 15
// 49.646 us; speedup vs baseline: 1.2806x; 1.2806x over previous
//
#include <hip/hip_runtime.h>
#include <stdint.h>

#define NF 24
#define FD 2000
#define VOCABSZ 48000
#define ED 64
#define H1D 64
#define H2D 32
#define NPAIR 276
#define BATCH 4096
#define NSEL 16
#define NTILE 256            // BATCH/16
#define PBASE 49152          // byte offset of P region (after 48KB emb)

typedef _Float16 f16x8 __attribute__((ext_vector_type(8)));
typedef _Float16 f16x2 __attribute__((ext_vector_type(2)));
typedef float f32x4 __attribute__((ext_vector_type(4)));

union U4 { f16x8 v; uint32_t u[4]; uint4 q; };
union H2U { f16x2 h; uint32_t u; };

__device__ __forceinline__ uint32_t pkrtz(float lo, float hi){
  uint32_t r; asm("v_cvt_pkrtz_f16_f32 %0, %1, %2" : "=v"(r) : "v"(lo), "v"(hi)); return r;
}
__device__ __forceinline__ uint32_t pk_add(uint32_t a, uint32_t b){
  uint32_t r; asm("v_pk_add_f16 %0, %1, %2" : "=v"(r) : "v"(a), "v"(b)); return r;
}
__device__ __forceinline__ uint32_t pk_mul(uint32_t a, uint32_t b){
  uint32_t r; asm("v_pk_mul_f16 %0, %1, %2" : "=v"(r) : "v"(a), "v"(b)); return r;
}
__device__ __forceinline__ uint32_t pk_relu(uint32_t a){
  uint32_t r; asm("v_pk_max_f16 %0, %1, %2" : "=v"(r) : "v"(a), "v"(0u)); return r;
}
__device__ __forceinline__ float fdot2(uint32_t a, uint32_t b, float c){
  H2U ua, ub; ua.u = a; ub.u = b;
  return __builtin_amdgcn_fdot2(ua.h, ub.h, c, false);
}
// VALU-pipe 16-lane-row prefix add (row_shr). Lane 15 ends with the row sum.
#define DPP_ADD(v, ctrl) \
  (v) += __int_as_float(__builtin_amdgcn_update_dpp(0, __float_as_int(v), (ctrl), 0xF, 0xF, true))

// Sum across the 4 16-lane rows via VALU-crossbar permlane swaps (no LDS port).
__device__ __forceinline__ float rowsum4(float v){
  float a = v, b;
  asm volatile("v_mov_b32 %0, %1" : "=v"(b) : "v"(a));
  asm volatile("v_permlane16_swap_b32 %0, %1" : "+v"(a), "+v"(b));
  a = a + b;
  asm volatile("v_mov_b32 %0, %1" : "=v"(b) : "v"(a));
  asm volatile("v_permlane32_swap_b32 %0, %1" : "+v"(a), "+v"(b));
  return a + b;
}

// ============ K1: fused projection + pair-MLP scores + cross-scalar g ============
// One block per 16-batch tile, 1024 threads (16 waves). LDS: [0,48KB) emb f16
// [f][b][k] swizzled (^(b&7)<<4); [48KB,144KB) P f16 [slab][b][o] swizzled.
// Phase B: unswapped MFMA + element-wise b16 stores (proven R10).
// Phase C: swapped MFMA + fdot2 g + permlane rowsums (proven R12).
__global__ __launch_bounds__(1024) void k_pair(
    const int* __restrict__ x, const float* __restrict__ tables,
    const float* __restrict__ w1, const float* __restrict__ b1,
    const float* __restrict__ w2, const float* __restrict__ b2,
    const float* __restrict__ w3, const float* __restrict__ b3,
    const float* __restrict__ proj_w,
    float* __restrict__ sgT, float* __restrict__ part){
  __shared__ __align__(16) char smem[147456];   // 144 KB
  const int tid  = threadIdx.x;
  const int bt   = blockIdx.x;
  const int lane = tid & 63;
  const int w    = tid >> 6;         // 0..15
  const int n    = lane & 15;
  const int kg   = lane >> 4;

  const int half = w >> 3;           // 0: Pt, 1: Pb
  const int oq   = (w >> 1) & 3;
  const int fg   = w & 1;
  const int isPt = (half == 0);
  const float b3v = b3[0];

  // ---- w1 B-frags + folded b1 (phase B operands) ----
  const int o = 16*oq + n;
  U4 wp0, wp1;
  {
    const float* wsrc = w1 + (size_t)(isPt ? 0 : ED)*H1D + o;
    #pragma unroll
    for(int j=0;j<8;j++) wp0.v[j] = (_Float16)wsrc[(kg*8+j)*H1D];
    #pragma unroll
    for(int j=0;j<8;j++) wp1.v[j] = (_Float16)wsrc[(32+kg*8+j)*H1D];
  }
  const float b1v = isPt ? b1[o] : 0.f;

  // ---- w2 frags (A-frag for swapped phase-C MFMA) ----
  U4 wf[2][2];   // [khalf][ohalf]
  #pragma unroll
  for(int kh=0;kh<2;kh++)
    #pragma unroll
    for(int nh=0;nh<2;nh++)
      #pragma unroll
      for(int q2=0;q2<4;q2++){
        float lo = w2[(kg*8 + 2*q2     + 32*kh)*H2D + n + 16*nh];
        float hi = w2[(kg*8 + 2*q2 + 1 + 32*kh)*H2D + n + 16*nh];
        wf[kh][nh].u[q2] = pkrtz(lo, hi);
      }
  // per-r b2/w3 (swapped D rows: o_local = kg*4+r + 16*oh)
  float b2r[2][4], w3r[2][4];
  #pragma unroll
  for(int oh=0;oh<2;oh++)
    #pragma unroll
    for(int r=0;r<4;r++){
      b2r[oh][r] = b2[16*oh + kg*4 + r];
      w3r[oh][r] = w3[16*oh + kg*4 + r];
    }

  // ---- proj_w slice packed f16 ----
  uint32_t pw2[8];
  #pragma unroll
  for(int j=0;j<8;j++) pw2[j] = pkrtz(proj_w[kg*16 + 2*j], proj_w[kg*16 + 2*j + 1]);

  // ---- phase A: gather 16 rows x 24 fields -> f16 LDS (swizzled) ----
  #pragma unroll
  for(int i=0;i<3;i++){
    int c = i*1024 + tid;         // 0..3071
    int rid = c >> 3;             // f*16 + b
    int qc = c & 7;               // 16B (8 f16) chunk
    int f = rid >> 4, b = rid & 15;
    int xv = x[(bt*16 + b)*NF + f];
    const float4* rp = (const float4*)(tables + ((size_t)f*VOCABSZ + (size_t)f*FD + (size_t)xv)*ED + qc*8);
    float4 v0 = rp[0], v1 = rp[1];
    uint4 pk;
    pk.x = pkrtz(v0.x, v0.y); pk.y = pkrtz(v0.z, v0.w);
    pk.z = pkrtz(v1.x, v1.y); pk.w = pkrtz(v1.z, v1.w);
    uint32_t db = ((uint32_t)(f*2048 + b*128 + qc*16)) ^ ((uint32_t)(b&7)<<4);
    *(uint4*)(smem + db) = pk;
  }
  __syncthreads();

  // ---- phase B: P = emb @ w1half (+b1) via MFMA; element-wise b16 stores ----
  {
    const uint32_t rswz = ((uint32_t)(n&7))<<4;
    const int slab0 = isPt ? 0 : 24;
    for(int ff=0; ff<12; ff++){
      int f = fg*12 + ff;
      U4 a0, a1;
      a0.q = *(const uint4*)(smem + (((uint32_t)(f*2048 + n*128      + kg*16)) ^ rswz));
      a1.q = *(const uint4*)(smem + (((uint32_t)(f*2048 + n*128 + 64 + kg*16)) ^ rswz));
      f32x4 acc = {b1v, b1v, b1v, b1v};
      acc = __builtin_amdgcn_mfma_f32_16x16x32_f16(a0.v, wp0.v, acc, 0,0,0);
      acc = __builtin_amdgcn_mfma_f32_16x16x32_f16(a1.v, wp1.v, acc, 0,0,0);
      int sl = slab0 + f;
      #pragma unroll
      for(int r=0;r<4;r++){
        int bo = kg*4 + r;
        uint32_t db = ((uint32_t)(PBASE + sl*2048 + bo*128 + o*2)) ^ (((uint32_t)(bo&7))<<4);
        *(_Float16*)(smem + db) = (_Float16)acc[r];
      }
    }
  }
  __syncthreads();

  // ---- phase C: pair loop over 16 waves (17-18 pairs each) ----
  {
    int p0, np;
    if(w < 4){ np = 18; p0 = w*18; } else { np = 17; p0 = 72 + (w-4)*17; }
    int ii = 0, rem = p0;
    while(rem >= (NF-1-ii)){ rem -= (NF-1-ii); ii++; }
    int jj = ii + 1 + rem;

    const uint32_t aswz = ((uint32_t)(n&7))<<4;
    const uint32_t rowoff = (uint32_t)n*128;
    const uint32_t qoff = (uint32_t)kg*16;
    const uint32_t kg32 = (uint32_t)kg*32;

    int cached_i = -1;
    U4 ta0, ta1, ei0, ei1;

    for(int t=0;t<np;t++){
      int p = p0 + t;
      if(ii != cached_i){
        uint32_t tb = (uint32_t)(PBASE + ii*2048) + rowoff;
        ta0.q = *(const uint4*)(smem + ((tb + qoff     ) ^ aswz));
        ta1.q = *(const uint4*)(smem + ((tb + qoff + 64) ^ aswz));
        uint32_t ebi = (uint32_t)(ii*2048) + rowoff + kg32;
        ei0.q = *(const uint4*)(smem + ((ebi     ) ^ aswz));
        ei1.q = *(const uint4*)(smem + ((ebi + 16) ^ aswz));
        cached_i = ii;
      }
      uint32_t ub = (uint32_t)(PBASE + (24+jj)*2048) + rowoff;
      uint4 c0 = *(const uint4*)(smem + ((ub + qoff     ) ^ aswz));
      uint4 c1 = *(const uint4*)(smem + ((ub + qoff + 64) ^ aswz));
      uint32_t ebj = (uint32_t)(jj*2048) + rowoff + kg32;
      U4 ej0, ej1;
      ej0.q = *(const uint4*)(smem + ((ebj     ) ^ aswz));
      ej1.q = *(const uint4*)(smem + ((ebj + 16) ^ aswz));

      U4 h0, h1;
      h0.u[0]=pk_relu(pk_add(ta0.u[0],c0.x)); h0.u[1]=pk_relu(pk_add(ta0.u[1],c0.y));
      h0.u[2]=pk_relu(pk_add(ta0.u[2],c0.z)); h0.u[3]=pk_relu(pk_add(ta0.u[3],c0.w));
      h1.u[0]=pk_relu(pk_add(ta1.u[0],c1.x)); h1.u[1]=pk_relu(pk_add(ta1.u[1],c1.y));
      h1.u[2]=pk_relu(pk_add(ta1.u[2],c1.z)); h1.u[3]=pk_relu(pk_add(ta1.u[3],c1.w));

      // SWAPPED operands: D[o_local][b=n] (proven R9/R10/R12)
      f32x4 acc0 = {0.f,0.f,0.f,0.f}, acc1 = {0.f,0.f,0.f,0.f};
      acc0 = __builtin_amdgcn_mfma_f32_16x16x32_f16(wf[0][0].v, h0.v, acc0, 0,0,0);
      acc0 = __builtin_amdgcn_mfma_f32_16x16x32_f16(wf[1][0].v, h1.v, acc0, 0,0,0);
      acc1 = __builtin_amdgcn_mfma_f32_16x16x32_f16(wf[0][1].v, h0.v, acc1, 0,0,0);
      acc1 = __builtin_amdgcn_mfma_f32_16x16x32_f16(wf[1][1].v, h1.v, acc1, 0,0,0);

      // g partial via packed f16 dot: lane covers b=n, k = kg*16..kg*16+15
      float gp = 0.f;
      #pragma unroll
      for(int q=0;q<4;q++) gp = fdot2(pk_mul(ei0.u[q], ej0.u[q]), pw2[q],   gp);
      #pragma unroll
      for(int q=0;q<4;q++) gp = fdot2(pk_mul(ei1.u[q], ej1.u[q]), pw2[4+q], gp);
      gp = rowsum4(gp);                      // g[p][b=n], all lanes

      // in-lane w3 dot over this lane's 8 o-elements, then sum across kg groups
      float tsum = 0.f;
      #pragma unroll
      for(int r=0;r<4;r++){
        float v0 = acc0[r] + b2r[0][r]; v0 = v0>0.f?v0:0.f;
        float v1 = acc1[r] + b2r[1][r]; v1 = v1>0.f?v1:0.f;
        tsum += v0*w3r[0][r] + v1*w3r[1][r];
      }
      tsum = rowsum4(tsum);
      float sc = tsum + b3v;                 // score[p][b=n], all lanes

      if(lane < 16) sgT[(size_t)bt*(NPAIR*16) + p*16 + lane] = sc * gp;

      // batch sum over b via DPP prefix adds (VALU pipe); lane 15 holds row sum
      float d = sc;
      DPP_ADD(d, 0x111);   // row_shr:1
      DPP_ADD(d, 0x112);   // row_shr:2
      DPP_ADD(d, 0x114);   // row_shr:4
      DPP_ADD(d, 0x118);   // row_shr:8
      if(lane == 15) part[(size_t)p*NTILE + bt] = d;

      if(++jj == NF){ ii++; jj = ii+1; }
    }
  }
}

// ============ K2: fused select (redundant per block) + final output ============
// 128 blocks x 2 tiles: halves the redundant means traffic (36 MB L2 total),
// final phase iterates 2 tiles per block (still 128 CUs busy).
__global__ __launch_bounds__(1024) void k_final(
    const int* __restrict__ x, const float* __restrict__ sgT,
    const float* __restrict__ part,
    const float* __restrict__ fc_w, const float* __restrict__ fc_b,
    const float* __restrict__ proj_b, const float* __restrict__ bias,
    float* __restrict__ out){
  __shared__ float means[NPAIR];
  __shared__ int sel[NSEL];
  int tid = threadIdx.x;

  // parallel means: 4 threads per pair, 64 tiles each, quad shfl combine
  {
    int p = tid >> 2, q = tid & 3;
    const float4* pp = (const float4*)(part + (size_t)p*NTILE + q*64);
    float4 s4 = {0.f,0.f,0.f,0.f};
    #pragma unroll
    for(int i=0;i<16;i++){
      float4 v = pp[i];
      s4.x += v.x; s4.y += v.y; s4.z += v.z; s4.w += v.w;
    }
    float s = (s4.x + s4.y) + (s4.z + s4.w);
    s += __shfl_xor(s, 1, 64);
    s += __shfl_xor(s, 2, 64);
    if(q == 0 && p < 256) means[p] = s;
    if(tid < 80){
      int p2 = 256 + (tid >> 2);
      const float4* pp2 = (const float4*)(part + (size_t)p2*NTILE + q*64);
      float4 t4 = {0.f,0.f,0.f,0.f};
      #pragma unroll
      for(int i=0;i<16;i++){
        float4 v = pp2[i];
        t4.x += v.x; t4.y += v.y; t4.z += v.z; t4.w += v.w;
      }
      float s2 = (t4.x + t4.y) + (t4.z + t4.w);
      s2 += __shfl_xor(s2, 1, 64);
      s2 += __shfl_xor(s2, 2, 64);
      if(q == 0) means[p2] = s2;
    }
  }
  __syncthreads();
  if(tid < 64){
    int l = tid;
    float v[5];
    #pragma unroll
    for(int q=0;q<5;q++){
      int i = l + q*64;
      v[q] = (i < NPAIR) ? means[i] : -3.0e38f;
    }
    for(int s=0;s<NSEL;s++){
      float bv = v[0]; int bslot = 0;
      #pragma unroll
      for(int q=1;q<5;q++){ if(v[q] > bv){ bv = v[q]; bslot = q; } }
      int bi = l + bslot*64;
      float cv = bv; int ci = bi;
      #pragma unroll
      for(int m=1;m<64;m<<=1){
        float ov = __shfl_xor(cv, m, 64);
        int   oi = __shfl_xor(ci, m, 64);
        if(ov > cv || (ov == cv && oi < ci)){ cv = ov; ci = oi; }
      }
      if(l == 0) sel[s] = ci;
      if(bi == ci) v[bslot] = -3.0e38f;
    }
  }
  __syncthreads();

  // final: 2 tiles per block, one wave per row; crossed = sum of selected sg
  int row = tid >> 6, lane = tid & 63;
  float fcb = fc_b[0], pjb = proj_b[0], bsv = bias[0];
  #pragma unroll
  for(int r2=0;r2<2;r2++){
    int bt = blockIdx.x*2 + r2;
    int brow = bt*16 + row;
    float v = 0.f;
    if(lane < NSEL){
      v = sgT[(size_t)bt*(NPAIR*16) + sel[lane]*16 + row];
    } else if(lane >= 32 && lane < 32+NF){
      int fl = lane - 32;
      v = fc_w[x[brow*NF + fl] + fl*FD];
    }
    #pragma unroll
    for(int m=1;m<64;m<<=1) v += __shfl_xor(v, m, 64);
    if(lane == 0) out[brow] = v + fcb + pjb + bsv;
  }
}

extern "C" void kernel_launch(void* const* d_in, const int* in_sizes, int n_in,
                              void* d_out, int out_size, void* d_ws, size_t ws_size,
                              hipStream_t stream){
  const int*   x      = (const int*)  d_in[0];
  const float* tables = (const float*)d_in[1];
  const float* fc_w   = (const float*)d_in[2];
  const float* fc_b   = (const float*)d_in[3];
  const float* w1     = (const float*)d_in[4];
  const float* b1     = (const float*)d_in[5];
  const float* w2     = (const float*)d_in[6];
  const float* b2     = (const float*)d_in[7];
  const float* w3     = (const float*)d_in[8];
  const float* b3     = (const float*)d_in[9];
  const float* proj_w = (const float*)d_in[10];
  const float* proj_b = (const float*)d_in[11];
  const float* bias   = (const float*)d_in[12];
  float* out = (float*)d_out;

  float* sgT  = (float*)d_ws;                          // 256*276*16 f32 [bt][p][b]
  float* part = sgT + (size_t)NTILE*NPAIR*16;          // 276*256 f32 [pair][tile]

  k_pair<<<NTILE, 1024, 0, stream>>>(x, tables, w1, b1, w2, b2, w3, b3, proj_w, sgT, part);
  k_final<<<NTILE/2, 1024, 0, stream>>>(x, sgT, part, fc_w, fc_b, proj_b, bias, out);
}

// Round 16
// 48.368 us; speedup vs baseline: 1.3144x; 1.0264x over previous
//
#include <hip/hip_runtime.h>
#include <stdint.h>

#define NF 24
#define FD 2000
#define VOCABSZ 48000
#define ED 64
#define H1D 64
#define H2D 32
#define NPAIR 276
#define BATCH 4096
#define NSEL 16
#define NTILE 256            // BATCH/16
#define PBASE 49152          // byte offset of P region (after 48KB emb)

typedef _Float16 f16x8 __attribute__((ext_vector_type(8)));
typedef _Float16 f16x2 __attribute__((ext_vector_type(2)));
typedef float f32x4 __attribute__((ext_vector_type(4)));

union U4 { f16x8 v; uint32_t u[4]; uint4 q; };
union H2U { f16x2 h; uint32_t u; };

__device__ __forceinline__ uint32_t pkrtz(float lo, float hi){
  uint32_t r; asm("v_cvt_pkrtz_f16_f32 %0, %1, %2" : "=v"(r) : "v"(lo), "v"(hi)); return r;
}
__device__ __forceinline__ uint32_t pk_add(uint32_t a, uint32_t b){
  uint32_t r; asm("v_pk_add_f16 %0, %1, %2" : "=v"(r) : "v"(a), "v"(b)); return r;
}
__device__ __forceinline__ uint32_t pk_mul(uint32_t a, uint32_t b){
  uint32_t r; asm("v_pk_mul_f16 %0, %1, %2" : "=v"(r) : "v"(a), "v"(b)); return r;
}
__device__ __forceinline__ uint32_t pk_relu(uint32_t a){
  uint32_t r; asm("v_pk_max_f16 %0, %1, %2" : "=v"(r) : "v"(a), "v"(0u)); return r;
}
__device__ __forceinline__ float fdot2(uint32_t a, uint32_t b, float c){
  H2U ua, ub; ua.u = a; ub.u = b;
  return __builtin_amdgcn_fdot2(ua.h, ub.h, c, false);
}
// VALU-pipe 16-lane-row prefix add (row_shr). Lane 15 ends with the row sum.
#define DPP_ADD(v, ctrl) \
  (v) += __int_as_float(__builtin_amdgcn_update_dpp(0, __float_as_int(v), (ctrl), 0xF, 0xF, true))

// ============ K1: fused projection + pair-MLP scores + cross-scalar g ============
// One block per 16-batch tile, 1024 threads (16 waves). LDS: [0,48KB) emb f16
// [f][b][k] swizzled (^(b&7)<<4); [48KB,144KB) P f16 [slab][b][o] swizzled.
// Phase B: unswapped MFMA, element-wise ds_write_b16 store (no shfl).
// Phase C: swapped MFMA, g via v_dot2_f32_f16, sg stored tile-major.
__global__ __launch_bounds__(1024) void k_pair(
    const int* __restrict__ x, const float* __restrict__ tables,
    const float* __restrict__ w1, const float* __restrict__ b1,
    const float* __restrict__ w2, const float* __restrict__ b2,
    const float* __restrict__ w3, const float* __restrict__ b3,
    const float* __restrict__ proj_w,
    float* __restrict__ sgT, float* __restrict__ part){
  __shared__ __align__(16) char smem[147456];   // 144 KB
  const int tid  = threadIdx.x;
  const int bt   = blockIdx.x;
  const int lane = tid & 63;
  const int w    = tid >> 6;         // 0..15
  const int n    = lane & 15;
  const int kg   = lane >> 4;

  const int half = w >> 3;           // 0: Pt, 1: Pb
  const int oq   = (w >> 1) & 3;
  const int fg   = w & 1;
  const int isPt = (half == 0);
  const float b3v = b3[0];

  // ---- w1 B-frags + folded b1 (phase B operands) ----
  const int o = 16*oq + n;
  U4 wp0, wp1;
  {
    const float* wsrc = w1 + (size_t)(isPt ? 0 : ED)*H1D + o;
    #pragma unroll
    for(int j=0;j<8;j++) wp0.v[j] = (_Float16)wsrc[(kg*8+j)*H1D];
    #pragma unroll
    for(int j=0;j<8;j++) wp1.v[j] = (_Float16)wsrc[(32+kg*8+j)*H1D];
  }
  const float b1v = isPt ? b1[o] : 0.f;

  // ---- w2 frags (A-frag for swapped phase-C MFMA) ----
  U4 wf[2][2];   // [khalf][ohalf]
  #pragma unroll
  for(int kh=0;kh<2;kh++)
    #pragma unroll
    for(int nh=0;nh<2;nh++)
      #pragma unroll
      for(int q2=0;q2<4;q2++){
        float lo = w2[(kg*8 + 2*q2     + 32*kh)*H2D + n + 16*nh];
        float hi = w2[(kg*8 + 2*q2 + 1 + 32*kh)*H2D + n + 16*nh];
        wf[kh][nh].u[q2] = pkrtz(lo, hi);
      }
  // per-r b2/w3 (swapped D rows: o_local = kg*4+r + 16*oh)
  float b2r[2][4], w3r[2][4];
  #pragma unroll
  for(int oh=0;oh<2;oh++)
    #pragma unroll
    for(int r=0;r<4;r++){
      b2r[oh][r] = b2[16*oh + kg*4 + r];
      w3r[oh][r] = w3[16*oh + kg*4 + r];
    }

  // ---- proj_w slice packed f16: pw2[j] = (proj_w[kg*16+2j], proj_w[kg*16+2j+1]) ----
  uint32_t pw2[8];
  #pragma unroll
  for(int j=0;j<8;j++) pw2[j] = pkrtz(proj_w[kg*16 + 2*j], proj_w[kg*16 + 2*j + 1]);

  // ---- phase A: gather 16 rows x 24 fields -> f16 LDS (swizzled) ----
  #pragma unroll
  for(int i=0;i<3;i++){
    int c = i*1024 + tid;         // 0..3071
    int rid = c >> 3;             // f*16 + b
    int qc = c & 7;               // 16B (8 f16) chunk
    int f = rid >> 4, b = rid & 15;
    int xv = x[(bt*16 + b)*NF + f];
    const float4* rp = (const float4*)(tables + ((size_t)f*VOCABSZ + (size_t)f*FD + (size_t)xv)*ED + qc*8);
    float4 v0 = rp[0], v1 = rp[1];
    uint4 pk;
    pk.x = pkrtz(v0.x, v0.y); pk.y = pkrtz(v0.z, v0.w);
    pk.z = pkrtz(v1.x, v1.y); pk.w = pkrtz(v1.z, v1.w);
    uint32_t db = ((uint32_t)(f*2048 + b*128 + qc*16)) ^ ((uint32_t)(b&7)<<4);
    *(uint4*)(smem + db) = pk;
  }
  __syncthreads();

  // ---- phase B: P = emb @ w1half (+b1) via MFMA; element-wise b16 stores ----
  {
    const uint32_t rswz = ((uint32_t)(n&7))<<4;
    const int slab0 = isPt ? 0 : 24;
    for(int ff=0; ff<12; ff++){
      int f = fg*12 + ff;
      U4 a0, a1;
      a0.q = *(const uint4*)(smem + (((uint32_t)(f*2048 + n*128      + kg*16)) ^ rswz));
      a1.q = *(const uint4*)(smem + (((uint32_t)(f*2048 + n*128 + 64 + kg*16)) ^ rswz));
      f32x4 acc = {b1v, b1v, b1v, b1v};
      acc = __builtin_amdgcn_mfma_f32_16x16x32_f16(a0.v, wp0.v, acc, 0,0,0);
      acc = __builtin_amdgcn_mfma_f32_16x16x32_f16(a1.v, wp1.v, acc, 0,0,0);
      int sl = slab0 + f;
      // D[b=kg*4+r][o=16*oq+n] -> direct per-element store, all lanes active
      #pragma unroll
      for(int r=0;r<4;r++){
        int bo = kg*4 + r;
        uint32_t db = ((uint32_t)(PBASE + sl*2048 + bo*128 + o*2)) ^ (((uint32_t)(bo&7))<<4);
        *(_Float16*)(smem + db) = (_Float16)acc[r];
      }
    }
  }
  __syncthreads();

  // ---- phase C: pair loop over 16 waves (17-18 pairs each) ----
  {
    int p0, np;
    if(w < 4){ np = 18; p0 = w*18; } else { np = 17; p0 = 72 + (w-4)*17; }
    int ii = 0, rem = p0;
    while(rem >= (NF-1-ii)){ rem -= (NF-1-ii); ii++; }
    int jj = ii + 1 + rem;

    const uint32_t aswz = ((uint32_t)(n&7))<<4;
    const uint32_t rowoff = (uint32_t)n*128;
    const uint32_t qoff = (uint32_t)kg*16;
    const uint32_t kg32 = (uint32_t)kg*32;

    int cached_i = -1;
    U4 ta0, ta1, ei0, ei1;

    for(int t=0;t<np;t++){
      int p = p0 + t;
      if(ii != cached_i){
        uint32_t tb = (uint32_t)(PBASE + ii*2048) + rowoff;
        ta0.q = *(const uint4*)(smem + ((tb + qoff     ) ^ aswz));
        ta1.q = *(const uint4*)(smem + ((tb + qoff + 64) ^ aswz));
        uint32_t ebi = (uint32_t)(ii*2048) + rowoff + kg32;
        ei0.q = *(const uint4*)(smem + ((ebi     ) ^ aswz));
        ei1.q = *(const uint4*)(smem + ((ebi + 16) ^ aswz));
        cached_i = ii;
      }
      uint32_t ub = (uint32_t)(PBASE + (24+jj)*2048) + rowoff;
      uint4 c0 = *(const uint4*)(smem + ((ub + qoff     ) ^ aswz));
      uint4 c1 = *(const uint4*)(smem + ((ub + qoff + 64) ^ aswz));
      uint32_t ebj = (uint32_t)(jj*2048) + rowoff + kg32;
      U4 ej0, ej1;
      ej0.q = *(const uint4*)(smem + ((ebj     ) ^ aswz));
      ej1.q = *(const uint4*)(smem + ((ebj + 16) ^ aswz));

      U4 h0, h1;
      h0.u[0]=pk_relu(pk_add(ta0.u[0],c0.x)); h0.u[1]=pk_relu(pk_add(ta0.u[1],c0.y));
      h0.u[2]=pk_relu(pk_add(ta0.u[2],c0.z)); h0.u[3]=pk_relu(pk_add(ta0.u[3],c0.w));
      h1.u[0]=pk_relu(pk_add(ta1.u[0],c1.x)); h1.u[1]=pk_relu(pk_add(ta1.u[1],c1.y));
      h1.u[2]=pk_relu(pk_add(ta1.u[2],c1.z)); h1.u[3]=pk_relu(pk_add(ta1.u[3],c1.w));

      // SWAPPED operands: D[o_local][b=n] (proven R9/R10)
      f32x4 acc0 = {0.f,0.f,0.f,0.f}, acc1 = {0.f,0.f,0.f,0.f};
      acc0 = __builtin_amdgcn_mfma_f32_16x16x32_f16(wf[0][0].v, h0.v, acc0, 0,0,0);
      acc0 = __builtin_amdgcn_mfma_f32_16x16x32_f16(wf[1][0].v, h1.v, acc0, 0,0,0);
      acc1 = __builtin_amdgcn_mfma_f32_16x16x32_f16(wf[0][1].v, h0.v, acc1, 0,0,0);
      acc1 = __builtin_amdgcn_mfma_f32_16x16x32_f16(wf[1][1].v, h1.v, acc1, 0,0,0);

      // g partial via packed f16 dot: lane covers b=n, k = kg*16..kg*16+15
      float gp = 0.f;
      #pragma unroll
      for(int q=0;q<4;q++) gp = fdot2(pk_mul(ei0.u[q], ej0.u[q]), pw2[q],   gp);
      #pragma unroll
      for(int q=0;q<4;q++) gp = fdot2(pk_mul(ei1.u[q], ej1.u[q]), pw2[4+q], gp);
      gp += __shfl_xor(gp, 16, 64);
      gp += __shfl_xor(gp, 32, 64);          // gp = g[p][b=n], all lanes

      // in-lane w3 dot over this lane's 8 o-elements, then sum across kg groups
      float tsum = 0.f;
      #pragma unroll
      for(int r=0;r<4;r++){
        float v0 = acc0[r] + b2r[0][r]; v0 = v0>0.f?v0:0.f;
        float v1 = acc1[r] + b2r[1][r]; v1 = v1>0.f?v1:0.f;
        tsum += v0*w3r[0][r] + v1*w3r[1][r];
      }
      tsum += __shfl_xor(tsum, 16, 64);
      tsum += __shfl_xor(tsum, 32, 64);
      float sc = tsum + b3v;                 // score[p][b=n], all lanes

      if(lane < 16) sgT[(size_t)bt*(NPAIR*16) + p*16 + lane] = sc * gp;

      // batch sum over b via DPP prefix adds (VALU pipe); lane 15 holds row sum
      float d = sc;
      DPP_ADD(d, 0x111);   // row_shr:1
      DPP_ADD(d, 0x112);   // row_shr:2
      DPP_ADD(d, 0x114);   // row_shr:4
      DPP_ADD(d, 0x118);   // row_shr:8
      if(lane == 15) part[(size_t)p*NTILE + bt] = d;

      if(++jj == NF){ ii++; jj = ii+1; }
    }
  }
}

// ============ K2: fused select (redundant per block) + final output ============
__global__ __launch_bounds__(1024) void k_final(
    const int* __restrict__ x, const float* __restrict__ sgT,
    const float* __restrict__ part,
    const float* __restrict__ fc_w, const float* __restrict__ fc_b,
    const float* __restrict__ proj_b, const float* __restrict__ bias,
    float* __restrict__ out){
  __shared__ float means[NPAIR];
  __shared__ int sel[NSEL];
  int tid = threadIdx.x;
  int bt = blockIdx.x;

  // parallel means: 4 threads per pair, 64 tiles each, quad shfl combine
  {
    int p = tid >> 2, q = tid & 3;
    const float4* pp = (const float4*)(part + (size_t)p*NTILE + q*64);
    float4 s4 = {0.f,0.f,0.f,0.f};
    #pragma unroll
    for(int i=0;i<16;i++){
      float4 v = pp[i];
      s4.x += v.x; s4.y += v.y; s4.z += v.z; s4.w += v.w;
    }
    float s = (s4.x + s4.y) + (s4.z + s4.w);
    s += __shfl_xor(s, 1, 64);
    s += __shfl_xor(s, 2, 64);
    if(q == 0 && p < 256) means[p] = s;
    if(tid < 80){
      int p2 = 256 + (tid >> 2);
      const float4* pp2 = (const float4*)(part + (size_t)p2*NTILE + q*64);
      float4 t4 = {0.f,0.f,0.f,0.f};
      #pragma unroll
      for(int i=0;i<16;i++){
        float4 v = pp2[i];
        t4.x += v.x; t4.y += v.y; t4.z += v.z; t4.w += v.w;
      }
      float s2 = (t4.x + t4.y) + (t4.z + t4.w);
      s2 += __shfl_xor(s2, 1, 64);
      s2 += __shfl_xor(s2, 2, 64);
      if(q == 0) means[p2] = s2;
    }
  }
  __syncthreads();
  if(tid < 64){
    int l = tid;
    float v[5];
    #pragma unroll
    for(int q=0;q<5;q++){
      int i = l + q*64;
      v[q] = (i < NPAIR) ? means[i] : -3.0e38f;
    }
    for(int s=0;s<NSEL;s++){
      float bv = v[0]; int bslot = 0;
      #pragma unroll
      for(int q=1;q<5;q++){ if(v[q] > bv){ bv = v[q]; bslot = q; } }
      int bi = l + bslot*64;
      float cv = bv; int ci = bi;
      #pragma unroll
      for(int m=1;m<64;m<<=1){
        float ov = __shfl_xor(cv, m, 64);
        int   oi = __shfl_xor(ci, m, 64);
        if(ov > cv || (ov == cv && oi < ci)){ cv = ov; ci = oi; }
      }
      if(l == 0) sel[s] = ci;
      if(bi == ci) v[bslot] = -3.0e38f;
    }
  }
  __syncthreads();

  // final: 16 rows per block, one wave per row; crossed = sum of selected sg
  int row = tid >> 6, lane = tid & 63;
  int brow = bt*16 + row;
  float v = 0.f;
  if(lane < NSEL){
    v = sgT[(size_t)bt*(NPAIR*16) + sel[lane]*16 + row];
  } else if(lane >= 32 && lane < 32+NF){
    int fl = lane - 32;
    v = fc_w[x[brow*NF + fl] + fl*FD];
  }
  #pragma unroll
  for(int m=1;m<64;m<<=1) v += __shfl_xor(v, m, 64);
  if(lane == 0) out[brow] = v + fc_b[0] + proj_b[0] + bias[0];
}

extern "C" void kernel_launch(void* const* d_in, const int* in_sizes, int n_in,
                              void* d_out, int out_size, void* d_ws, size_t ws_size,
                              hipStream_t stream){
  const int*   x      = (const int*)  d_in[0];
  const float* tables = (const float*)d_in[1];
  const float* fc_w   = (const float*)d_in[2];
  const float* fc_b   = (const float*)d_in[3];
  const float* w1     = (const float*)d_in[4];
  const float* b1     = (const float*)d_in[5];
  const float* w2     = (const float*)d_in[6];
  const float* b2     = (const float*)d_in[7];
  const float* w3     = (const float*)d_in[8];
  const float* b3     = (const float*)d_in[9];
  const float* proj_w = (const float*)d_in[10];
  const float* proj_b = (const float*)d_in[11];
  const float* bias   = (const float*)d_in[12];
  float* out = (float*)d_out;

  float* sgT  = (float*)d_ws;                          // 256*276*16 f32 [bt][p][b]
  float* part = sgT + (size_t)NTILE*NPAIR*16;          // 276*256 f32 [pair][tile]

  k_pair<<<NTILE, 1024, 0, stream>>>(x, tables, w1, b1, w2, b2, w3, b3, proj_w, sgT, part);
  k_final<<<NTILE, 1024, 0, stream>>>(x, sgT, part, fc_w, fc_b, proj_b, bias, out);
}